// Round 3
// baseline (200.276 us; speedup 1.0000x reference)
//
#include <hip/hip_runtime.h>

// INT8-style BERT embeddings + approx LayerNorm, MI355X (gfx950).
// H=768 = 3 groups/lane * 64 lanes * 4 ints (int4 vector loads).
// One wave (64 lanes) per token -> shuffle reductions only, no LDS/barriers.
// R2: one-pass sum/sumsq (interleaved butterfly), sqrtf instead of the
//     8-iter NR-divide chain (NR converges to fp32 sqrt anyway), and
//     nontemporal output stores so the 101 MB write-once output doesn't
//     evict word_table rows from L2/L3.
// R3: __builtin_nontemporal_store needs a native vector type, not HIP's
//     float4 class -> use ext_vector_type(4) float.

constexpr int H_DIM = 768;
constexpr int TPB = 256;          // 4 waves
constexpr int TOK_PER_BLK = 4;    // one token per wave

typedef float nfloat4 __attribute__((ext_vector_type(4)));

__global__ __launch_bounds__(TPB) void bert_emb_kernel(
    const int* __restrict__ input_ids,
    const int* __restrict__ token_type_ids,
    const int* __restrict__ word_table,
    const float* __restrict__ word_scale,
    const int* __restrict__ pos_table,
    const float* __restrict__ pos_scale,
    const int* __restrict__ type_table,
    const float* __restrict__ type_scale,
    const float* __restrict__ ln_w,
    const float* __restrict__ ln_b,
    float* __restrict__ out,
    int n_tokens, int S)
{
    const int wave = threadIdx.x >> 6;
    const int lane = threadIdx.x & 63;
    const int token = blockIdx.x * TOK_PER_BLK + wave;
    if (token >= n_tokens) return;

    const int s   = token % S;              // position id
    const int wid = input_ids[token];
    const int tt  = token_type_ids[token];

    const float ws = word_scale[0];
    const float ps = pos_scale[0];
    const float ts = type_scale[0];

    const int4* __restrict__ wrow = (const int4*)(word_table + (long long)wid * H_DIM);
    const int4* __restrict__ prow = (const int4*)(pos_table  + (long long)s   * H_DIM);
    const int4* __restrict__ trow = (const int4*)(type_table + (long long)tt  * H_DIM);

    // gather + dequant + add: 12 elements/lane held in registers.
    // One pass: accumulate sum and sum-of-squares together.
    float e[3][4];
    float sum = 0.f;
    float sq  = 0.f;
#pragma unroll
    for (int j = 0; j < 3; ++j) {
        const int g = j * 64 + lane;
        const int4 w4 = wrow[g];
        const int4 p4 = prow[g];
        const int4 t4 = trow[g];
        e[j][0] = (float)w4.x * ws + (float)p4.x * ps + (float)t4.x * ts;
        e[j][1] = (float)w4.y * ws + (float)p4.y * ps + (float)t4.y * ts;
        e[j][2] = (float)w4.z * ws + (float)p4.z * ps + (float)t4.z * ts;
        e[j][3] = (float)w4.w * ws + (float)p4.w * ps + (float)t4.w * ts;
#pragma unroll
        for (int k = 0; k < 4; ++k) {
            sum += e[j][k];
            sq  += e[j][k] * e[j][k];
        }
    }

    // single 6-level butterfly, both accumulators interleaved (independent
    // shuffles per level -> ~half the serial latency of two trees)
#pragma unroll
    for (int off = 1; off < 64; off <<= 1) {
        sum += __shfl_xor(sum, off);
        sq  += __shfl_xor(sq, off);
    }
    const float mean = sum * (1.0f / (float)H_DIM);
    float var = sq * (1.0f / (float)H_DIM) - mean * mean;
    var = var < 0.f ? 0.f : var;   // guard fp32 cancellation

    // Reference's 8-iter Newton-Raphson converges to fp32 sqrt for any
    // realistic var; sqrtf matches within ~1 ULP (abs err ~2e-6 in out).
    const float inv = 1.0f / (sqrtf(var) + 1e-12f);

    // epilogue: normalize, affine, coalesced nontemporal float4 stores
    nfloat4* __restrict__ orow = (nfloat4*)(out + (long long)token * H_DIM);
    const float4* __restrict__ lwv = (const float4*)ln_w;
    const float4* __restrict__ lbv = (const float4*)ln_b;
#pragma unroll
    for (int j = 0; j < 3; ++j) {
        const int g = j * 64 + lane;
        const float4 lw = lwv[g];
        const float4 lb = lbv[g];
        nfloat4 o;
        o.x = lw.x * ((e[j][0] - mean) * inv) + lb.x;
        o.y = lw.y * ((e[j][1] - mean) * inv) + lb.y;
        o.z = lw.z * ((e[j][2] - mean) * inv) + lb.z;
        o.w = lw.w * ((e[j][3] - mean) * inv) + lb.w;
        __builtin_nontemporal_store(o, &orow[g]);
    }
}

extern "C" void kernel_launch(void* const* d_in, const int* in_sizes, int n_in,
                              void* d_out, int out_size, void* d_ws, size_t ws_size,
                              hipStream_t stream) {
    const int*   input_ids      = (const int*)d_in[0];
    const int*   token_type_ids = (const int*)d_in[1];
    const int*   word_table     = (const int*)d_in[2];
    const float* word_scale     = (const float*)d_in[3];
    const int*   pos_table      = (const int*)d_in[4];
    const float* pos_scale      = (const float*)d_in[5];
    const int*   type_table     = (const int*)d_in[6];
    const float* type_scale     = (const float*)d_in[7];
    const float* ln_w           = (const float*)d_in[8];
    const float* ln_b           = (const float*)d_in[9];
    float* out = (float*)d_out;

    const int n_tokens = in_sizes[0];        // B*S
    const int S = in_sizes[4] / H_DIM;       // pos_table rows

    const int blocks = (n_tokens + TOK_PER_BLK - 1) / TOK_PER_BLK;
    bert_emb_kernel<<<blocks, TPB, 0, stream>>>(
        input_ids, token_type_ids, word_table, word_scale,
        pos_table, pos_scale, type_table, type_scale,
        ln_w, ln_b, out, n_tokens, S);
}